// Round 6
// baseline (96.695 us; speedup 1.0000x reference)
//
#include <hip/hip_runtime.h>

#define N_NODES 50000
#define N_EDGES 100000
#define NUM_RELS 200
#define DIM 64
#define CAP 512
#define TILES 8        // CAP/64 entries per tile
#define COLS 8         // cols per wave (8 waves of a 512-block = 64 cols)

// ---- workspace layout (int32 elements) ----
#define OFF_LAST 0
#define OFF_CUR  50000
#define OFF_BN   50200
#define OFF_BS   (50200 + NUM_RELS * CAP)

// Fused-kernel block split: first BUCKET_BLKS blocks do bucketing, rest do self GEMM
#define BUCKET_BLKS 98                      // ceil(50000/512)
#define SELF_BLKS   782                     // ceil(50000/64)

__global__ void init_kernel(int* __restrict__ ws) {
    int i = blockIdx.x * 256 + threadIdx.x;
    if (i < N_NODES) ws[OFF_LAST + i] = -1;
    if (i < NUM_RELS) ws[OFF_CUR + i] = 0;
}

__global__ void edge_max_kernel(const int* __restrict__ edges, int* __restrict__ ws) {
    int e = blockIdx.x * 256 + threadIdx.x;
    if (e < N_EDGES) atomicMax(&ws[OFF_LAST + edges[e * 3 + 2]], e);
}

// acc[COLS] += h-chunk (8 per-lane floats) x W rows (wave-uniform -> s_load)
__device__ __forceinline__ void body8c(float acc[COLS], const float* __restrict__ Wr,
                                       float4 a, float4 b) {
    float hv[8] = {a.x, a.y, a.z, a.w, b.x, b.y, b.z, b.w};
#pragma unroll
    for (int i = 0; i < 8; ++i) {
#pragma unroll
        for (int o = 0; o < COLS; ++o)
            acc[o] = fmaf(hv[i], Wr[i * DIM + o], acc[o]);
    }
}

// Fused: blocks [0,BUCKET_BLKS) bucket nodes by rel; blocks [BUCKET_BLKS,..) do
// out = h @ wself (64-node tile x 8 col-waves). No dependency between the parts.
__global__ __launch_bounds__(512) void bucket_self_kernel(
    const float* __restrict__ h,
    const int* __restrict__ edges,
    const float* __restrict__ wself,
    int* __restrict__ ws,
    float* __restrict__ out)
{
    if (blockIdx.x < BUCKET_BLKS) {
        int n = blockIdx.x * 512 + threadIdx.x;
        if (n >= N_NODES) return;
        int li = ws[OFF_LAST + n];
        if (li < 0) return;
        int r = edges[li * 3 + 1];
        int s = edges[li * 3 + 0];
        int pos = atomicAdd(&ws[OFF_CUR + r], 1);
        if (pos < CAP) {
            ws[OFF_BN + r * CAP + pos] = n;
            ws[OFF_BS + r * CAP + pos] = s;
        }
        return;
    }

    int tileb = blockIdx.x - BUCKET_BLKS;
    int lane = threadIdx.x & 63;
    int w = __builtin_amdgcn_readfirstlane(threadIdx.x >> 6);  // 0..7 -> col chunk
    int n = tileb * 64 + lane;
    bool valid = n < N_NODES;
    int nc = valid ? n : (N_NODES - 1);
    const float* hp = h + (size_t)nc * DIM;
    const float* Wc = wself + w * COLS;

    float acc[COLS];
#pragma unroll
    for (int o = 0; o < COLS; ++o) acc[o] = 0.f;

#pragma unroll
    for (int ib = 0; ib < DIM; ib += 8) {
        float4 a = *(const float4*)(hp + ib);
        float4 b = *(const float4*)(hp + ib + 4);
        body8c(acc, Wc + ib * DIM, a, b);
    }

    if (valid) {
        float* op = out + (size_t)n * DIM + w * COLS;
#pragma unroll
        for (int o = 0; o < COLS; o += 4)
            *(float4*)(op + o) = make_float4(acc[o], acc[o+1], acc[o+2], acc[o+3]);
    }
}

// out[n] += h[src] @ weight[rel].  Block = (rel, 64-entry tile) x 8 col-waves.
__global__ __launch_bounds__(512) void msg_kernel(const float* __restrict__ h,
                                                  const float* __restrict__ weight,
                                                  const int* __restrict__ ws,
                                                  float* __restrict__ out) {
    int rel  = blockIdx.x >> 3;
    int tile = blockIdx.x & 7;
    int c = ws[OFF_CUR + rel];
    if (c > CAP) c = CAP;
    int start = tile * 64;
    if (start >= c) return;

    int lane = threadIdx.x & 63;
    int w = __builtin_amdgcn_readfirstlane(threadIdx.x >> 6);
    int pos = start + lane;
    bool valid = pos < c;
    int cp = valid ? pos : (c - 1);
    int n = ws[OFF_BN + rel * CAP + cp];
    int s = ws[OFF_BS + rel * CAP + cp];
    const float* hp = h + (size_t)s * DIM;
    const float* Wc = weight + (size_t)rel * DIM * DIM + w * COLS;

    float acc[COLS];
#pragma unroll
    for (int o = 0; o < COLS; ++o) acc[o] = 0.f;

#pragma unroll
    for (int ib = 0; ib < DIM; ib += 8) {
        float4 a = *(const float4*)(hp + ib);
        float4 b = *(const float4*)(hp + ib + 4);
        body8c(acc, Wc + ib * DIM, a, b);
    }

    if (valid) {
        float* op = out + (size_t)n * DIM + w * COLS;
#pragma unroll
        for (int o = 0; o < COLS; o += 4) {
            float4 cur = *(const float4*)(op + o);
            *(float4*)(op + o) = make_float4(cur.x + acc[o], cur.y + acc[o+1],
                                             cur.z + acc[o+2], cur.w + acc[o+3]);
        }
    }
}

extern "C" void kernel_launch(void* const* d_in, const int* in_sizes, int n_in,
                              void* d_out, int out_size, void* d_ws, size_t ws_size,
                              hipStream_t stream) {
    const float* h      = (const float*)d_in[0];
    const int*   edges  = (const int*)d_in[1];
    const float* weight = (const float*)d_in[2];
    const float* wself  = (const float*)d_in[3];
    float* out = (float*)d_out;
    int* ws = (int*)d_ws;

    init_kernel<<<(N_NODES + 255) / 256, 256, 0, stream>>>(ws);
    edge_max_kernel<<<(N_EDGES + 255) / 256, 256, 0, stream>>>(edges, ws);
    bucket_self_kernel<<<BUCKET_BLKS + SELF_BLKS, 512, 0, stream>>>(h, edges, wself, ws, out);
    msg_kernel<<<NUM_RELS * TILES, 512, 0, stream>>>(h, weight, ws, out);
}

// Round 7
// 68.784 us; speedup vs baseline: 1.4058x; 1.4058x over previous
//
#include <hip/hip_runtime.h>

#define N_NODES 50000
#define N_EDGES 100000
#define NUM_RELS 200
#define DIM 64
#define CAP 512
#define TILES 8          // CAP/64 tiles per rel
#define HPAD 68          // padded h_lds row stride (floats); 68*4B=272B keeps 16B align

// ---- workspace layout (int32 elements) ----
#define OFF_LAST 0
#define OFF_CUR  50000
#define OFF_BN   50200
#define OFF_BS   (50200 + NUM_RELS * CAP)

#define BUCKET_BLKS 196   // ceil(50000/256)
#define SELF_BLKS   782   // ceil(50000/64)

__global__ void init_kernel(int* __restrict__ ws) {
    int i = blockIdx.x * 256 + threadIdx.x;
    if (i < N_NODES) ws[OFF_LAST + i] = -1;
    if (i < NUM_RELS) ws[OFF_CUR + i] = 0;
}

__global__ void edge_max_kernel(const int* __restrict__ edges, int* __restrict__ ws) {
    int e = blockIdx.x * 256 + threadIdx.x;
    if (e < N_EDGES) atomicMax(&ws[OFF_LAST + edges[e * 3 + 2]], e);
}

// Inner loop: thread (e4 = tid>>4, c4 = tid&15) owns 4 entries x 4 cols.
__device__ __forceinline__ void gemm44(const float* __restrict__ Hl,
                                       const float* __restrict__ Wl,
                                       int e4, int c4, float acc[4][4]) {
#pragma unroll 8
    for (int k = 0; k < DIM; ++k) {
        float4 hv = *(const float4*)&Hl[k * HPAD + e4 * 4];  // 4 entries, broadcast x16 lanes
        float4 wv = *(const float4*)&Wl[k * DIM + c4 * 4];   // 4 cols,    broadcast x4 lanes
        float hvv[4] = {hv.x, hv.y, hv.z, hv.w};
        float wvv[4] = {wv.x, wv.y, wv.z, wv.w};
#pragma unroll
        for (int i = 0; i < 4; ++i)
#pragma unroll
            for (int j = 0; j < 4; ++j)
                acc[i][j] = fmaf(hvv[i], wvv[j], acc[i][j]);
    }
}

// Fused: blocks [0,BUCKET_BLKS) bucket nodes; rest do out = h @ wself,
// 64-node tile per block, register-tiled 4x4 with W and H^T in LDS.
__global__ __launch_bounds__(256) void bucket_self_kernel(
    const float* __restrict__ h,
    const int* __restrict__ edges,
    const float* __restrict__ wself,
    int* __restrict__ ws,
    float* __restrict__ out)
{
    __shared__ float Wl[DIM * DIM];
    __shared__ float Hl[DIM * HPAD];

    if (blockIdx.x < BUCKET_BLKS) {
        int n = blockIdx.x * 256 + threadIdx.x;
        if (n < N_NODES) {
            int li = ws[OFF_LAST + n];
            if (li >= 0) {
                int r = edges[li * 3 + 1];
                int s = edges[li * 3 + 0];
                int pos = atomicAdd(&ws[OFF_CUR + r], 1);
                if (pos < CAP) {
                    ws[OFF_BN + r * CAP + pos] = n;
                    ws[OFF_BS + r * CAP + pos] = s;
                }
            }
        }
        return;
    }

    int tile = blockIdx.x - BUCKET_BLKS;
    int base = tile * 64;
    int t = threadIdx.x;

    // stage W: 4 coalesced float4 per thread
    {
        const float4* wg = (const float4*)wself;
        float4* wl4 = (float4*)Wl;
#pragma unroll
        for (int j = 0; j < 4; ++j) wl4[t + j * 256] = wg[t + j * 256];
    }
    // stage H transposed: lane e = entry, wave q = k-quarter; 2-lanes/bank writes
    {
        int e = t & 63, q = t >> 6;
        int n = base + e; if (n >= N_NODES) n = N_NODES - 1;
        const float* hp = h + (size_t)n * DIM + q * 16;
#pragma unroll
        for (int j = 0; j < 4; ++j) {
            float4 v = *(const float4*)(hp + j * 4);
            int k0 = q * 16 + j * 4;
            Hl[(k0 + 0) * HPAD + e] = v.x;
            Hl[(k0 + 1) * HPAD + e] = v.y;
            Hl[(k0 + 2) * HPAD + e] = v.z;
            Hl[(k0 + 3) * HPAD + e] = v.w;
        }
    }
    __syncthreads();

    int c4 = t & 15, e4 = t >> 4;
    float acc[4][4];
#pragma unroll
    for (int i = 0; i < 4; ++i)
#pragma unroll
        for (int j = 0; j < 4; ++j) acc[i][j] = 0.f;

    gemm44(Hl, Wl, e4, c4, acc);

#pragma unroll
    for (int i = 0; i < 4; ++i) {
        int n = base + e4 * 4 + i;
        if (n < N_NODES)
            *(float4*)(out + (size_t)n * DIM + c4 * 4) =
                make_float4(acc[i][0], acc[i][1], acc[i][2], acc[i][3]);
    }
}

// msg: block = (rel, 64-entry tile); out[n] += h[src] @ weight[rel]
__global__ __launch_bounds__(256) void msg_kernel(const float* __restrict__ h,
                                                  const float* __restrict__ weight,
                                                  const int* __restrict__ ws,
                                                  float* __restrict__ out) {
    __shared__ float Wl[DIM * DIM];
    __shared__ float Hl[DIM * HPAD];

    int rel  = blockIdx.x >> 3;
    int tile = blockIdx.x & 7;
    int c = ws[OFF_CUR + rel];
    if (c > CAP) c = CAP;
    int start = tile * 64;
    if (start >= c) return;          // block-uniform exit

    int t = threadIdx.x;
    const int* bn = ws + OFF_BN + rel * CAP;
    const int* bs = ws + OFF_BS + rel * CAP;

    {
        const float4* wg = (const float4*)(weight + (size_t)rel * DIM * DIM);
        float4* wl4 = (float4*)Wl;
#pragma unroll
        for (int j = 0; j < 4; ++j) wl4[t + j * 256] = wg[t + j * 256];
    }
    {
        int e = t & 63, q = t >> 6;
        int pos = start + e; if (pos >= c) pos = c - 1;
        int s = bs[pos];
        const float* hp = h + (size_t)s * DIM + q * 16;
#pragma unroll
        for (int j = 0; j < 4; ++j) {
            float4 v = *(const float4*)(hp + j * 4);
            int k0 = q * 16 + j * 4;
            Hl[(k0 + 0) * HPAD + e] = v.x;
            Hl[(k0 + 1) * HPAD + e] = v.y;
            Hl[(k0 + 2) * HPAD + e] = v.z;
            Hl[(k0 + 3) * HPAD + e] = v.w;
        }
    }
    __syncthreads();

    int c4 = t & 15, e4 = t >> 4;
    float acc[4][4];
#pragma unroll
    for (int i = 0; i < 4; ++i)
#pragma unroll
        for (int j = 0; j < 4; ++j) acc[i][j] = 0.f;

    gemm44(Hl, Wl, e4, c4, acc);

#pragma unroll
    for (int i = 0; i < 4; ++i) {
        int pos = start + e4 * 4 + i;
        if (pos < c) {
            int n = bn[pos];
            float* op = out + (size_t)n * DIM + c4 * 4;
            float4 cur = *(const float4*)op;
            *(float4*)op = make_float4(cur.x + acc[i][0], cur.y + acc[i][1],
                                       cur.z + acc[i][2], cur.w + acc[i][3]);
        }
    }
}

extern "C" void kernel_launch(void* const* d_in, const int* in_sizes, int n_in,
                              void* d_out, int out_size, void* d_ws, size_t ws_size,
                              hipStream_t stream) {
    const float* h      = (const float*)d_in[0];
    const int*   edges  = (const int*)d_in[1];
    const float* weight = (const float*)d_in[2];
    const float* wself  = (const float*)d_in[3];
    float* out = (float*)d_out;
    int* ws = (int*)d_ws;

    init_kernel<<<(N_NODES + 255) / 256, 256, 0, stream>>>(ws);
    edge_max_kernel<<<(N_EDGES + 255) / 256, 256, 0, stream>>>(edges, ws);
    bucket_self_kernel<<<BUCKET_BLKS + SELF_BLKS, 256, 0, stream>>>(h, edges, wself, ws, out);
    msg_kernel<<<NUM_RELS * TILES, 256, 0, stream>>>(h, weight, ws, out);
}